// Round 5
// baseline (3468.645 us; speedup 1.0000x reference)
//
#include <hip/hip_runtime.h>
#include <hip/hip_bf16.h>

// DSS bundle propagation: 3 graphs x (2-layer SpMM + L2norm + average).
// R4: cross-XCD-exclusive bucket partition + fused bucketed SpMM.
//   - partition: counts[bucket][block] -> bucket-major scan -> scatter; each
//     (bucket,block) destination sub-range is block-exclusive -> no cross-XCD
//     partial-line writebacks (R3's 8x write amplification).
//   - bucketed SpMM: one block per 128-row bucket, LDS fp32 acc tile,
//     per-edge 256-B gather + LDS atomicAdd, single coalesced row write.
//     Layer 2 fused with L2norm/average/pack epilogue.
//
// Output rows: [UI_u(U) | UB_u(U) | BI_b(NB) | UB_b(NB) | UI_i(NI) | BI_i(NI)]

#define D 64
#define BKT_SHIFT 7
#define BKT_ROWS 128
#define MAX_NBKT 1184      // >= ceil(150000/128) = 1172
#define NPB 128            // partition blocks

// ---------- partition: per-block bucket histogram ----------
__global__ void part_count(const int* __restrict__ rows, int E, int chunk, int NBKT,
                           int* __restrict__ counts) {
    __shared__ int hist[MAX_NBKT];
    int blk = blockIdx.x;
    for (int i = threadIdx.x; i < NBKT; i += blockDim.x) hist[i] = 0;
    __syncthreads();
    int s = blk * chunk, e = min(E, s + chunk);
    for (int i = s + threadIdx.x; i < e; i += blockDim.x)
        atomicAdd(&hist[rows[i] >> BKT_SHIFT], 1);
    __syncthreads();
    for (int b = threadIdx.x; b < NBKT; b += blockDim.x)
        counts[(size_t)b * NPB + blk] = hist[b];   // bucket-major for scan
}

// ---------- generic exclusive scan (256-block + bsum + add) ----------
__global__ void scan_block(const int* __restrict__ cnt, int n,
                           int* __restrict__ outp, int* __restrict__ bsum) {
    __shared__ int s[256];
    int tid = threadIdx.x;
    int i = blockIdx.x * 256 + tid;
    int v = (i < n) ? cnt[i] : 0;
    s[tid] = v;
    __syncthreads();
    #pragma unroll
    for (int off = 1; off < 256; off <<= 1) {
        int t = (tid >= off) ? s[tid - off] : 0;
        __syncthreads();
        s[tid] += t;
        __syncthreads();
    }
    if (i < n) outp[i] = s[tid] - v;
    if (tid == 255) bsum[blockIdx.x] = s[255];
}

__global__ void scan_bsums(int* __restrict__ bsum, int nb) {
    __shared__ int s[1024];
    __shared__ int carry_s;
    int tid = threadIdx.x;
    if (tid == 0) carry_s = 0;
    __syncthreads();
    for (int base = 0; base < nb; base += 1024) {
        int i = base + tid;
        int v = (i < nb) ? bsum[i] : 0;
        s[tid] = v;
        __syncthreads();
        for (int off = 1; off < 1024; off <<= 1) {
            int t = (tid >= off) ? s[tid - off] : 0;
            __syncthreads();
            s[tid] += t;
            __syncthreads();
        }
        if (i < nb) bsum[i] = carry_s + s[tid] - v;
        __syncthreads();
        if (tid == 1023) carry_s += s[1023];
        __syncthreads();
    }
}

__global__ void add_offsets(int* __restrict__ outp, const int* __restrict__ bsum,
                            int n, int E) {
    int i = blockIdx.x * blockDim.x + threadIdx.x;
    if (i < n) outp[i] += bsum[i >> 8];
    if (i == 0) outp[n] = E;
}

// ---------- partition: scatter packed records into block-exclusive ranges ----------
// rec.x = (row_local << 24) | col   (col < 2^24), rec.y = bitcast(val)
__global__ void part_scatter(const int* __restrict__ rows, const int* __restrict__ cols,
                             const float* __restrict__ vals, int E, int chunk, int NBKT,
                             const int* __restrict__ base, int2* __restrict__ ev) {
    __shared__ int cur[MAX_NBKT];
    int blk = blockIdx.x;
    for (int b = threadIdx.x; b < NBKT; b += blockDim.x)
        cur[b] = base[(size_t)b * NPB + blk];
    __syncthreads();
    int s = blk * chunk, e = min(E, s + chunk);
    for (int i = s + threadIdx.x; i < e; i += blockDim.x) {
        int r = rows[i];
        int b = r >> BKT_SHIFT;
        int p = atomicAdd(&cur[b], 1);
        ev[p] = make_int2(((r & (BKT_ROWS - 1)) << 24) | cols[i], __float_as_int(vals[i]));
    }
}

// ---------- bucketed SpMM layer 1 ----------
// One block per bucket; LDS acc[128][64]; wave per edge; write rows once.
__global__ void bspmm_l1(const int2* __restrict__ ev, const int* __restrict__ base,
                         const float* __restrict__ A, const float* __restrict__ B,
                         int nA, int n, float* __restrict__ f1) {
    __shared__ float acc[BKT_ROWS * D];   // 32 KB
    int b = blockIdx.x;
    for (int i = threadIdx.x; i < BKT_ROWS * D; i += blockDim.x) acc[i] = 0.0f;
    __syncthreads();
    int s = base[(size_t)b * NPB];
    int e = base[(size_t)(b + 1) * NPB];
    int wave = threadIdx.x >> 6, lane = threadIdx.x & 63;
    int nw = blockDim.x >> 6;             // 16 waves
    int j = s + wave;
    for (; j + 3 * nw < e; j += 4 * nw) {
        int2 r0 = ev[j], r1 = ev[j + nw], r2 = ev[j + 2 * nw], r3 = ev[j + 3 * nw];
        int c0 = r0.x & 0xFFFFFF, c1 = r1.x & 0xFFFFFF;
        int c2 = r2.x & 0xFFFFFF, c3 = r3.x & 0xFFFFFF;
        const float* p0 = (c0 < nA) ? A + (size_t)c0 * D : B + (size_t)(c0 - nA) * D;
        const float* p1 = (c1 < nA) ? A + (size_t)c1 * D : B + (size_t)(c1 - nA) * D;
        const float* p2 = (c2 < nA) ? A + (size_t)c2 * D : B + (size_t)(c2 - nA) * D;
        const float* p3 = (c3 < nA) ? A + (size_t)c3 * D : B + (size_t)(c3 - nA) * D;
        float x0 = p0[lane], x1 = p1[lane], x2 = p2[lane], x3 = p3[lane];
        atomicAdd(&acc[((r0.x >> 24) << 6) + lane], __int_as_float(r0.y) * x0);
        atomicAdd(&acc[((r1.x >> 24) << 6) + lane], __int_as_float(r1.y) * x1);
        atomicAdd(&acc[((r2.x >> 24) << 6) + lane], __int_as_float(r2.y) * x2);
        atomicAdd(&acc[((r3.x >> 24) << 6) + lane], __int_as_float(r3.y) * x3);
    }
    for (; j < e; j += nw) {
        int2 r0 = ev[j];
        int c0 = r0.x & 0xFFFFFF;
        const float* p0 = (c0 < nA) ? A + (size_t)c0 * D : B + (size_t)(c0 - nA) * D;
        atomicAdd(&acc[((r0.x >> 24) << 6) + lane], __int_as_float(r0.y) * p0[lane]);
    }
    __syncthreads();
    int lo = b << BKT_SHIFT;
    int cnt = (min(n, lo + BKT_ROWS) - lo) * D;
    for (int i = threadIdx.x; i < cnt; i += blockDim.x)
        f1[(size_t)lo * D + i] = acc[i];
}

// ---------- bucketed SpMM layer 2 + fused epilogue ----------
__global__ void bspmm_l2_fin(const int2* __restrict__ ev, const int* __restrict__ base,
                             const float* __restrict__ f1,
                             const float* __restrict__ A, const float* __restrict__ B,
                             int nA, int n, float* __restrict__ out,
                             long long offA, long long offB) {
    __shared__ float acc[BKT_ROWS * D];   // 32 KB
    int b = blockIdx.x;
    for (int i = threadIdx.x; i < BKT_ROWS * D; i += blockDim.x) acc[i] = 0.0f;
    __syncthreads();
    int s = base[(size_t)b * NPB];
    int e = base[(size_t)(b + 1) * NPB];
    int wave = threadIdx.x >> 6, lane = threadIdx.x & 63;
    int nw = blockDim.x >> 6;
    int j = s + wave;
    for (; j + 3 * nw < e; j += 4 * nw) {
        int2 r0 = ev[j], r1 = ev[j + nw], r2 = ev[j + 2 * nw], r3 = ev[j + 3 * nw];
        float x0 = f1[(size_t)(r0.x & 0xFFFFFF) * D + lane];
        float x1 = f1[(size_t)(r1.x & 0xFFFFFF) * D + lane];
        float x2 = f1[(size_t)(r2.x & 0xFFFFFF) * D + lane];
        float x3 = f1[(size_t)(r3.x & 0xFFFFFF) * D + lane];
        atomicAdd(&acc[((r0.x >> 24) << 6) + lane], __int_as_float(r0.y) * x0);
        atomicAdd(&acc[((r1.x >> 24) << 6) + lane], __int_as_float(r1.y) * x1);
        atomicAdd(&acc[((r2.x >> 24) << 6) + lane], __int_as_float(r2.y) * x2);
        atomicAdd(&acc[((r3.x >> 24) << 6) + lane], __int_as_float(r3.y) * x3);
    }
    for (; j < e; j += nw) {
        int2 r0 = ev[j];
        atomicAdd(&acc[((r0.x >> 24) << 6) + lane],
                  __int_as_float(r0.y) * f1[(size_t)(r0.x & 0xFFFFFF) * D + lane]);
    }
    __syncthreads();
    int lo = b << BKT_SHIFT;
    for (int rl = wave; rl < BKT_ROWS; rl += nw) {
        int r = lo + rl;
        if (r >= n) continue;
        float x2v = acc[(rl << 6) + lane];
        float x1v = f1[(size_t)r * D + lane];
        float x0v = (r < nA) ? A[(size_t)r * D + lane] : B[(size_t)(r - nA) * D + lane];
        float s1 = x1v * x1v;
        float s2 = x2v * x2v;
        #pragma unroll
        for (int m = 32; m > 0; m >>= 1) {
            s1 += __shfl_xor(s1, m, 64);
            s2 += __shfl_xor(s2, m, 64);
        }
        float n1 = fmaxf(sqrtf(s1), 1e-12f);
        float n2 = fmaxf(sqrtf(s2), 1e-12f);
        float y = (x0v + x1v / n1 + x2v / n2) * (1.0f / 3.0f);
        long long orow = (r < nA) ? (offA + r) : (offB + (r - nA));
        out[orow * D + lane] = y;
    }
}

extern "C" void kernel_launch(void* const* d_in, const int* in_sizes, int n_in,
                              void* d_out, int out_size, void* d_ws, size_t ws_size,
                              hipStream_t stream) {
    const float* users   = (const float*)d_in[0];
    const float* items   = (const float*)d_in[1];
    const float* bundles = (const float*)d_in[2];
    const float* ui_vals = (const float*)d_in[3];
    const float* bi_vals = (const float*)d_in[4];
    const float* ub_vals = (const float*)d_in[5];
    const int* ui_rows = (const int*)d_in[6];
    const int* ui_cols = (const int*)d_in[7];
    const int* bi_rows = (const int*)d_in[8];
    const int* bi_cols = (const int*)d_in[9];
    const int* ub_rows = (const int*)d_in[10];
    const int* ub_cols = (const int*)d_in[11];

    const int U  = in_sizes[0] / D;
    const int NI = in_sizes[1] / D;
    const int NB = in_sizes[2] / D;
    const int E_ui = in_sizes[3];
    const int E_bi = in_sizes[4];
    const int E_ub = in_sizes[5];

    float* out = (float*)d_out;

    const int maxRows = U + NI;                       // 150000
    const int maxE    = E_ui;                         // 2M
    const int maxNBKT = (maxRows + BKT_ROWS - 1) / BKT_ROWS;   // 1172
    const int maxM    = maxNBKT * NPB;                // 150016

    char* ws = (char*)d_ws;
    float* f1     = (float*)ws;  ws += (size_t)maxRows * D * sizeof(float);  // 38.4 MB
    int2*  ev     = (int2*)ws;   ws += (size_t)maxE * sizeof(int2);          // 16 MB
    int*   counts = (int*)ws;    ws += (size_t)maxM * sizeof(int);           // 0.6 MB
    int*   basep  = (int*)ws;    ws += (size_t)(maxM + 1) * sizeof(int);     // 0.6 MB
    int*   bsum   = (int*)ws;    ws += 1024 * sizeof(int);
    (void)ws_size;

    const long long off_UI_u = 0;
    const long long off_UB_u = U;
    const long long off_BI_b = 2LL * U;
    const long long off_UB_b = 2LL * U + NB;
    const long long off_UI_i = 2LL * U + 2LL * NB;
    const long long off_BI_i = 2LL * U + 2LL * NB + NI;

    auto run_prop = [&](const int* rows, const int* cols, const float* vals, int E,
                        const float* A, const float* B, int nA, int nB,
                        long long offA, long long offB) {
        const int n = nA + nB;
        const int NBKT = (n + BKT_ROWS - 1) / BKT_ROWS;
        const int m = NBKT * NPB;
        const int chunk = (E + NPB - 1) / NPB;
        const int sblocks = (m + 255) / 256;

        part_count<<<NPB, 256, 0, stream>>>(rows, E, chunk, NBKT, counts);
        scan_block<<<sblocks, 256, 0, stream>>>(counts, m, basep, bsum);
        scan_bsums<<<1, 1024, 0, stream>>>(bsum, sblocks);
        add_offsets<<<sblocks, 256, 0, stream>>>(basep, bsum, m, E);
        part_scatter<<<NPB, 256, 0, stream>>>(rows, cols, vals, E, chunk, NBKT, basep, ev);

        bspmm_l1<<<NBKT, 1024, 0, stream>>>(ev, basep, A, B, nA, n, f1);
        bspmm_l2_fin<<<NBKT, 1024, 0, stream>>>(ev, basep, f1, A, B, nA, n,
                                                out, offA, offB);
    };

    run_prop(ui_rows, ui_cols, ui_vals, E_ui, users, items, U, NI, off_UI_u, off_UI_i);
    run_prop(bi_rows, bi_cols, bi_vals, E_bi, bundles, items, NB, NI, off_BI_b, off_BI_i);
    run_prop(ub_rows, ub_cols, ub_vals, E_ub, users, bundles, U, NB, off_UB_u, off_UB_b);
}

// Round 6
// 840.370 us; speedup vs baseline: 4.1275x; 4.1275x over previous
//
#include <hip/hip_runtime.h>
#include <hip/hip_bf16.h>

// DSS bundle propagation: 3 graphs x (2-layer SpMM + L2norm + average).
// R5: block-exclusive bucket partition (R4, proven) + per-bucket CSR finalize
// (LDS histogram+scan, block-exclusive contiguous writes) + R2's proven
// 4-deep-pipelined row-gather SpMM with fused epilogue. No LDS fp atomics
// (R4's 750 us bspmm failure), no random 8-B scatter (R2's 125 MB fill_csr).
//
// Output rows: [UI_u(U) | UB_u(U) | BI_b(NB) | UB_b(NB) | UI_i(NI) | BI_i(NI)]

#define D 64
#define BKT_SHIFT 7
#define BKT_ROWS 128
#define MAX_NBKT 1184      // >= ceil(150000/128) = 1172
#define NPB 128            // partition blocks

// ---------- partition: per-block bucket histogram ----------
__global__ void part_count(const int* __restrict__ rows, int E, int chunk, int NBKT,
                           int* __restrict__ counts) {
    __shared__ int hist[MAX_NBKT];
    int blk = blockIdx.x;
    for (int i = threadIdx.x; i < NBKT; i += blockDim.x) hist[i] = 0;
    __syncthreads();
    int s = blk * chunk, e = min(E, s + chunk);
    for (int i = s + threadIdx.x; i < e; i += blockDim.x)
        atomicAdd(&hist[rows[i] >> BKT_SHIFT], 1);
    __syncthreads();
    for (int b = threadIdx.x; b < NBKT; b += blockDim.x)
        counts[(size_t)b * NPB + blk] = hist[b];   // bucket-major for scan
}

// ---------- generic exclusive scan ----------
__global__ void scan_block(const int* __restrict__ cnt, int n,
                           int* __restrict__ outp, int* __restrict__ bsum) {
    __shared__ int s[256];
    int tid = threadIdx.x;
    int i = blockIdx.x * 256 + tid;
    int v = (i < n) ? cnt[i] : 0;
    s[tid] = v;
    __syncthreads();
    #pragma unroll
    for (int off = 1; off < 256; off <<= 1) {
        int t = (tid >= off) ? s[tid - off] : 0;
        __syncthreads();
        s[tid] += t;
        __syncthreads();
    }
    if (i < n) outp[i] = s[tid] - v;
    if (tid == 255) bsum[blockIdx.x] = s[255];
}

__global__ void scan_bsums(int* __restrict__ bsum, int nb) {
    __shared__ int s[1024];
    __shared__ int carry_s;
    int tid = threadIdx.x;
    if (tid == 0) carry_s = 0;
    __syncthreads();
    for (int base = 0; base < nb; base += 1024) {
        int i = base + tid;
        int v = (i < nb) ? bsum[i] : 0;
        s[tid] = v;
        __syncthreads();
        for (int off = 1; off < 1024; off <<= 1) {
            int t = (tid >= off) ? s[tid - off] : 0;
            __syncthreads();
            s[tid] += t;
            __syncthreads();
        }
        if (i < nb) bsum[i] = carry_s + s[tid] - v;
        __syncthreads();
        if (tid == 1023) carry_s += s[1023];
        __syncthreads();
    }
}

__global__ void add_offsets(int* __restrict__ outp, const int* __restrict__ bsum,
                            int n, int E) {
    int i = blockIdx.x * blockDim.x + threadIdx.x;
    if (i < n) outp[i] += bsum[i >> 8];
    if (i == 0) outp[n] = E;
}

// ---------- partition: scatter packed records into block-exclusive ranges ----------
// rec.x = (row_local << 25) | col   (col < 2^25), rec.y = bitcast(val)
__global__ void part_scatter(const int* __restrict__ rows, const int* __restrict__ cols,
                             const float* __restrict__ vals, int E, int chunk, int NBKT,
                             const int* __restrict__ base, int2* __restrict__ ev) {
    __shared__ int cur[MAX_NBKT];
    int blk = blockIdx.x;
    for (int b = threadIdx.x; b < NBKT; b += blockDim.x)
        cur[b] = base[(size_t)b * NPB + blk];
    __syncthreads();
    int s = blk * chunk, e = min(E, s + chunk);
    for (int i = s + threadIdx.x; i < e; i += blockDim.x) {
        int r = rows[i];
        int b = r >> BKT_SHIFT;
        int p = atomicAdd(&cur[b], 1);
        unsigned rec = ((unsigned)(r & (BKT_ROWS - 1)) << 25) | (unsigned)cols[i];
        ev[p] = make_int2((int)rec, __float_as_int(vals[i]));
    }
}

// ---------- per-bucket CSR finalize ----------
// One block per bucket: LDS row histogram (1 int atomic/edge), 128-entry scan,
// emit row_ptr, rewrite records row-sorted into ev2 (block-exclusive range).
__global__ void csr_finalize(const int2* __restrict__ ev, const int* __restrict__ base,
                             int n, int E, int* __restrict__ row_ptr,
                             int2* __restrict__ ev2) {
    __shared__ int cnt[BKT_ROWS];
    __shared__ int sc[BKT_ROWS];
    int b = blockIdx.x;
    int tid = threadIdx.x;
    int s = base[(size_t)b * NPB];
    int e = base[(size_t)(b + 1) * NPB];
    if (tid < BKT_ROWS) cnt[tid] = 0;
    __syncthreads();
    for (int j = s + tid; j < e; j += blockDim.x)
        atomicAdd(&cnt[((unsigned)ev[j].x) >> 25], 1);
    __syncthreads();
    // inclusive Hillis-Steele scan of cnt into sc
    if (tid < BKT_ROWS) sc[tid] = cnt[tid];
    __syncthreads();
    #pragma unroll
    for (int d = 1; d < BKT_ROWS; d <<= 1) {
        int t = 0;
        if (tid < BKT_ROWS && tid >= d) t = sc[tid - d];
        __syncthreads();
        if (tid < BKT_ROWS) sc[tid] += t;
        __syncthreads();
    }
    int lo = b << BKT_SHIFT;
    // exclusive start for row tid; reuse cnt as write cursor
    if (tid < BKT_ROWS) {
        int excl = s + sc[tid] - cnt[tid];
        if (lo + tid < n) row_ptr[lo + tid] = excl;
        cnt[tid] = excl;
    }
    if (b == 0 && tid == 0) row_ptr[n] = E;
    __syncthreads();
    for (int j = s + tid; j < e; j += blockDim.x) {
        int2 r = ev[j];
        int rl = (int)(((unsigned)r.x) >> 25);
        int p = atomicAdd(&cnt[rl], 1);
        ev2[p] = make_int2(r.x & 0x1FFFFFF, r.y);
    }
}

// ---------- SpMM layer 1 (4-deep pipelined row-gather) ----------
__global__ void spmm_l1(const int* __restrict__ row_ptr, const int2* __restrict__ ev,
                        const float* __restrict__ A, const float* __restrict__ B,
                        int nA, int n, float* __restrict__ f1) {
    long long t = (long long)blockIdx.x * blockDim.x + threadIdx.x;
    int r = (int)(t >> 6);
    int d = (int)(t & 63);
    if (r >= n) return;
    int beg = row_ptr[r], end = row_ptr[r + 1];
    float acc = 0.0f;
    int j = beg;
    for (; j + 4 <= end; j += 4) {
        int2 e0 = ev[j], e1 = ev[j + 1], e2 = ev[j + 2], e3 = ev[j + 3];
        const float* p0 = (e0.x < nA) ? A + (size_t)e0.x * D : B + (size_t)(e0.x - nA) * D;
        const float* p1 = (e1.x < nA) ? A + (size_t)e1.x * D : B + (size_t)(e1.x - nA) * D;
        const float* p2 = (e2.x < nA) ? A + (size_t)e2.x * D : B + (size_t)(e2.x - nA) * D;
        const float* p3 = (e3.x < nA) ? A + (size_t)e3.x * D : B + (size_t)(e3.x - nA) * D;
        float x0 = p0[d], x1 = p1[d], x2 = p2[d], x3 = p3[d];
        acc = fmaf(__int_as_float(e0.y), x0, acc);
        acc = fmaf(__int_as_float(e1.y), x1, acc);
        acc = fmaf(__int_as_float(e2.y), x2, acc);
        acc = fmaf(__int_as_float(e3.y), x3, acc);
    }
    for (; j < end; ++j) {
        int2 e = ev[j];
        const float* p = (e.x < nA) ? A + (size_t)e.x * D : B + (size_t)(e.x - nA) * D;
        acc = fmaf(__int_as_float(e.y), p[d], acc);
    }
    f1[(size_t)r * D + d] = acc;
}

// ---------- SpMM layer 2 fused with epilogue ----------
__global__ void spmm_l2_fin(const int* __restrict__ row_ptr, const int2* __restrict__ ev,
                            const float* __restrict__ f1,
                            const float* __restrict__ A, const float* __restrict__ B,
                            int nA, int n, float* __restrict__ out,
                            long long offA, long long offB) {
    long long t = (long long)blockIdx.x * blockDim.x + threadIdx.x;
    int r = (int)(t >> 6);
    int d = (int)(t & 63);
    if (r >= n) return;
    int beg = row_ptr[r], end = row_ptr[r + 1];
    float acc = 0.0f;
    int j = beg;
    for (; j + 4 <= end; j += 4) {
        int2 e0 = ev[j], e1 = ev[j + 1], e2 = ev[j + 2], e3 = ev[j + 3];
        float x0 = f1[(size_t)e0.x * D + d];
        float x1 = f1[(size_t)e1.x * D + d];
        float x2 = f1[(size_t)e2.x * D + d];
        float x3 = f1[(size_t)e3.x * D + d];
        acc = fmaf(__int_as_float(e0.y), x0, acc);
        acc = fmaf(__int_as_float(e1.y), x1, acc);
        acc = fmaf(__int_as_float(e2.y), x2, acc);
        acc = fmaf(__int_as_float(e3.y), x3, acc);
    }
    for (; j < end; ++j) {
        int2 e = ev[j];
        acc = fmaf(__int_as_float(e.y), f1[(size_t)e.x * D + d], acc);
    }
    float x1r = f1[(size_t)r * D + d];
    float s1 = x1r * x1r;
    float s2 = acc * acc;
    #pragma unroll
    for (int m = 32; m > 0; m >>= 1) {
        s1 += __shfl_xor(s1, m, 64);
        s2 += __shfl_xor(s2, m, 64);
    }
    float n1 = fmaxf(sqrtf(s1), 1e-12f);
    float n2 = fmaxf(sqrtf(s2), 1e-12f);
    float x0 = (r < nA) ? A[(size_t)r * D + d] : B[(size_t)(r - nA) * D + d];
    float y = (x0 + x1r / n1 + acc / n2) * (1.0f / 3.0f);
    long long orow = (r < nA) ? (offA + r) : (offB + (r - nA));
    out[orow * D + d] = y;
}

extern "C" void kernel_launch(void* const* d_in, const int* in_sizes, int n_in,
                              void* d_out, int out_size, void* d_ws, size_t ws_size,
                              hipStream_t stream) {
    const float* users   = (const float*)d_in[0];
    const float* items   = (const float*)d_in[1];
    const float* bundles = (const float*)d_in[2];
    const float* ui_vals = (const float*)d_in[3];
    const float* bi_vals = (const float*)d_in[4];
    const float* ub_vals = (const float*)d_in[5];
    const int* ui_rows = (const int*)d_in[6];
    const int* ui_cols = (const int*)d_in[7];
    const int* bi_rows = (const int*)d_in[8];
    const int* bi_cols = (const int*)d_in[9];
    const int* ub_rows = (const int*)d_in[10];
    const int* ub_cols = (const int*)d_in[11];

    const int U  = in_sizes[0] / D;
    const int NI = in_sizes[1] / D;
    const int NB = in_sizes[2] / D;
    const int E_ui = in_sizes[3];
    const int E_bi = in_sizes[4];
    const int E_ub = in_sizes[5];

    float* out = (float*)d_out;

    const int maxRows = U + NI;                                // 150000
    const int maxE    = E_ui;                                  // 2M
    const int maxNBKT = (maxRows + BKT_ROWS - 1) / BKT_ROWS;   // 1172
    const int maxM    = maxNBKT * NPB;

    char* ws = (char*)d_ws;
    float* f1      = (float*)ws;  ws += (size_t)maxRows * D * sizeof(float);   // 38.4 MB
    int2*  ev      = (int2*)ws;   ws += (size_t)maxE * sizeof(int2);           // 16 MB
    int2*  ev2     = (int2*)ws;   ws += (size_t)maxE * sizeof(int2);           // 16 MB
    int*   counts  = (int*)ws;    ws += (size_t)maxM * sizeof(int);            // 0.6 MB
    int*   basep   = (int*)ws;    ws += (size_t)(maxM + 1) * sizeof(int);      // 0.6 MB
    int*   row_ptr = (int*)ws;    ws += (size_t)(maxRows + 1) * sizeof(int);   // 0.6 MB
    int*   bsum    = (int*)ws;    ws += 1024 * sizeof(int);
    (void)ws_size;

    const long long off_UI_u = 0;
    const long long off_UB_u = U;
    const long long off_BI_b = 2LL * U;
    const long long off_UB_b = 2LL * U + NB;
    const long long off_UI_i = 2LL * U + 2LL * NB;
    const long long off_BI_i = 2LL * U + 2LL * NB + NI;

    auto run_prop = [&](const int* rows, const int* cols, const float* vals, int E,
                        const float* A, const float* B, int nA, int nB,
                        long long offA, long long offB) {
        const int n = nA + nB;
        const int NBKT = (n + BKT_ROWS - 1) / BKT_ROWS;
        const int m = NBKT * NPB;
        const int chunk = (E + NPB - 1) / NPB;
        const int sblocks = (m + 255) / 256;

        part_count<<<NPB, 256, 0, stream>>>(rows, E, chunk, NBKT, counts);
        scan_block<<<sblocks, 256, 0, stream>>>(counts, m, basep, bsum);
        scan_bsums<<<1, 1024, 0, stream>>>(bsum, sblocks);
        add_offsets<<<sblocks, 256, 0, stream>>>(basep, bsum, m, E);
        part_scatter<<<NPB, 256, 0, stream>>>(rows, cols, vals, E, chunk, NBKT, basep, ev);
        csr_finalize<<<NBKT, 256, 0, stream>>>(ev, basep, n, E, row_ptr, ev2);

        const long long T = (long long)n * D;
        const int rblocks = (int)((T + 255) / 256);
        spmm_l1<<<rblocks, 256, 0, stream>>>(row_ptr, ev2, A, B, nA, n, f1);
        spmm_l2_fin<<<rblocks, 256, 0, stream>>>(row_ptr, ev2, f1, A, B, nA, n,
                                                 out, offA, offB);
    };

    run_prop(ui_rows, ui_cols, ui_vals, E_ui, users, items, U, NI, off_UI_u, off_UI_i);
    run_prop(bi_rows, bi_cols, bi_vals, E_bi, bundles, items, NB, NI, off_BI_b, off_BI_i);
    run_prop(ub_rows, ub_cols, ub_vals, E_ub, users, bundles, U, NB, off_UB_u, off_UB_b);
}